// Round 12
// baseline (519.194 us; speedup 1.0000x reference)
//
#include <hip/hip_runtime.h>

#define T_OBS 512
#define RDW   100          // dwords per batch-row in s_h (200 halves; 100 mod 32 = 4 -> free 2-way only)
#define PSTR  20           // s_pr row stride in dwords (12 used; 80B rows, 16B-aligned; 2-way only)
#define L2E   1.44269504089f

typedef float    f32x4 __attribute__((ext_vector_type(4)));
typedef _Float16 f16x8 __attribute__((ext_vector_type(8)));

#define MF(A,B,C) __builtin_amdgcn_mfma_f32_16x16x32_f16(A,B,C,0,0,0)

__device__ __forceinline__ unsigned f2h(float f){
    union { _Float16 h; unsigned short u; } v; v.h=(_Float16)f; return (unsigned)v.u;
}

// lgkm-only barrier (proven safe R11): leaves out-stores / x-loads in flight.
__device__ __forceinline__ void bar_lds(){
    asm volatile("s_waitcnt lgkmcnt(0)" ::: "memory");
    __builtin_amdgcn_sched_barrier(0);
    __builtin_amdgcn_s_barrier();
    __builtin_amdgcn_sched_barrier(0);
}

// prescaled gates: i,f,o carry -log2e; g carries +2*log2e.
// single-rcp gate block: R = rcp(ui*uf*ug*uo). 5 exp2 + 2 rcp.
__device__ __forceinline__ float act1(const f32x4 a, float& c){
    const float Ei=__builtin_amdgcn_exp2f(a[0]), Ef=__builtin_amdgcn_exp2f(a[1]);
    const float Eg=__builtin_amdgcn_exp2f(a[2]), Eo=__builtin_amdgcn_exp2f(a[3]);
    const float ui=1.f+Ei, uf=1.f+Ef, ug=1.f+Eg, uo=1.f+Eo;
    const float P=ui*uf, Q=ug*uo;
    const float R=__builtin_amdgcn_rcpf(P*Q);
    const float aP=R*Q, aQ=R*P;
    const float ig=aP*uf, fg=aP*ui;
    const float og=aQ*ug;
    const float gg=fmaf(aQ*uo,-2.f,1.f);
    c = fg*c + ig*gg;
    const float Ec=__builtin_amdgcn_exp2f(2.f*L2E*c);
    return og*fmaf(__builtin_amdgcn_rcpf(1.f+Ec),-2.f,1.f);
}

// LDS s_h per batch-row q (halves, stride 200): parity region par at 96*par;
// within region, unit u occupies halves {2u, 2u+1} = {h0_u, h1_u} (interleaved).
// MERGED ROLES: wave w owns L0 tile w and L1 tile w -> lane (q,rg) owns unit u=4w+rg
// for BOTH layers -> steady h-write is one conflict-free b32.
__global__ __launch_bounds__(768, 1) void lstm2_v12(
    const float* __restrict__ x,
    const float* __restrict__ Wih0, const float* __restrict__ Whh0,
    const float* __restrict__ bih0, const float* __restrict__ bhh0,
    const float* __restrict__ Wih1, const float* __restrict__ Whh1,
    const float* __restrict__ bih1, const float* __restrict__ bhh1,
    const float* __restrict__ Wlin, const float* __restrict__ blin,
    const int* __restrict__ fut,
    float* __restrict__ out)
{
    __shared__ __attribute__((aligned(16))) _Float16 s_h[16 * 2 * RDW];
    __shared__ __attribute__((aligned(16))) float s_pr[2][16 * PSTR];
    unsigned* const s32 = (unsigned*)s_h;

    const int tid  = threadIdx.x;
    const int w    = tid >> 6, lane = tid & 63;
    const int q    = lane & 15, rg = lane >> 4;

    for (int i = tid; i < 16 * 2 * RDW; i += 768) s32[i % (16*RDW)] = 0u;  // zero (idempotent)
    // (simple zero pass; region fully overwritten before any semantically-live read)

    // gate of this lane's A-rows: gate = q&3 (uniform per lane)
    const float sgl = ((q & 3) == 2) ? 2.f * L2E : -L2E;

    // ---- A fragments: K=96 interleaved (even k -> h0 weights, odd k -> h1 weights) ----
    // L0 tile w: even k = Whh0 col k/2, odd k = 0.  L1 tile w: even = Wih1, odd = Whh1.
    f16x8 a0h[3], a0l[3], a1h[3], a1l[3];
    {
        const int rp = 16 * w + q;
        const int r0 = (rp & 3) * 48 + (rp >> 2);      // permuted row rp = unit*4 + gate
        #pragma unroll
        for (int s = 0; s < 3; ++s)
            #pragma unroll
            for (int j = 0; j < 8; ++j) {
                const int k = 32 * s + 8 * rg + j;
                const int u = k >> 1;
                const int od = k & 1;
                const float v1 = (od ? Whh1[r0 * 48 + u] : Wih1[r0 * 48 + u]) * sgl;
                const float v0 = od ? 0.f : Whh0[r0 * 48 + u] * sgl;
                const _Float16 h1w = (_Float16)v1;
                const _Float16 h0w = (_Float16)v0;
                a1h[s][j] = h1w;  a1l[s][j] = (_Float16)(v1 - (float)h1w);
                a0h[s][j] = h0w;  a0l[s][j] = (_Float16)(v0 - (float)h0w);
            }
    }

    const float sg4[4] = { -L2E, -L2E, 2.f * L2E, -L2E };   // (i,f,g,o)
    const int u = 4 * w + rg;                                // this lane's unit (both layers)
    f32x4 bv0, bv1, wi0v;
    #pragma unroll
    for (int g = 0; g < 4; ++g) {
        bv0[g]  = (bih0[g*48+u] + bhh0[g*48+u]) * sg4[g];
        bv1[g]  = (bih1[g*48+u] + bhh1[g*48+u]) * sg4[g];
        wi0v[g] = Wih0[g * 48 + u] * sg4[g];
    }
    const float wl = Wlin[u];

    const int ko0 = 8 * rg, ko1 = 32 + 8 * rg, ko2 = 64 + 8 * rg;  // halves within region
    const int F    = fut[0];
    const int TT   = T_OBS + F;
    const int bb0  = blockIdx.x * 16;
    const float bl = blin[0];
    const int xrow = (bb0 + q) * T_OBS;
    const int nbh  = q * 2 * RDW;          // halves base of row q
    const int nbd  = q * RDW;              // dword base of row q
    const int prw  = lane * PSTR;          // (only lanes<16 use: row q=lane)

    float cc0 = 0.f, cc1 = 0.f;
    const f32x4 z4 = { 0.f, 0.f, 0.f, 0.f };

    __syncthreads();

    // ---- tick 0 (peeled): all waves compute their L0 tile, h0(-1)=0, h1(-1)=0 ----
    {
        const float x0 = x[xrow];
        const f32x4 a = bv0 + wi0v * x0;
        const float h0f = act1(a, cc0);
        s32[nbd + u] = f2h(h0f);            // parity 0: {h0(0), h1(-1)=0}
    }
    bar_lds();
    float xcur = x[xrow + 1];

    // steady tick TAU_: every wave computes L0 step TAU_ and L1 step TAU_-1.
    // WB_ = write parity base (dwords), RB_ = read parity base (halves).
#define STEADY(TAU_, WB_, RB_) do {                                              \
    const f16x8 B0 = *(const f16x8*)(s_h + nbh + (RB_) + ko0);                   \
    const f16x8 B1 = *(const f16x8*)(s_h + nbh + (RB_) + ko1);                   \
    const f16x8 B2 = *(const f16x8*)(s_h + nbh + (RB_) + ko2);                   \
    const float xnxt = x[xrow + (((TAU_) + 1 < T_OBS) ? (TAU_) + 1 : T_OBS - 1)]; \
    f32x4 g1a = MF(a1h[0], B0, bv1);                                             \
    g1a = MF(a1l[0], B0, g1a);                                                   \
    g1a = MF(a1h[1], B1, g1a);                                                   \
    f32x4 g1b = MF(a1l[1], B1, z4);                                              \
    g1b = MF(a1h[2], B2, g1b);                                                   \
    g1b = MF(a1l[2], B2, g1b);                                                   \
    f32x4 g0a = MF(a0h[0], B0, bv0);                                             \
    g0a = MF(a0l[0], B0, g0a);                                                   \
    g0a = MF(a0h[1], B1, g0a);                                                   \
    f32x4 g0b = MF(a0l[1], B1, z4);                                              \
    g0b = MF(a0h[2], B2, g0b);                                                   \
    g0b = MF(a0l[2], B2, g0b);                                                   \
    if ((TAU_) >= 2 && w == 0) {            /* gather out(TAU_-2): 12 partials */ \
        const int b = lane >> 2, jj = lane & 3;                                  \
        const float* pr = &s_pr[((TAU_) - 1) & 1][b * PSTR + jj * 3];            \
        float gv = pr[0] + pr[1] + pr[2];                                        \
        gv += __shfl_xor(gv, 1); gv += __shfl_xor(gv, 2);                        \
        if (jj == 0) out[(bb0 + b) * TT + ((TAU_) - 2)] = gv + bl;               \
    }                                                                            \
    const f32x4 G1 = g1a + g1b;                                                  \
    const float h1f = act1(G1, cc1);                                             \
    const f32x4 G0 = g0a + g0b + wi0v * xcur;                                    \
    const float h0f = act1(G0, cc0);                                             \
    s32[nbd + (WB_) + u] = f2h(h0f) | (f2h(h1f) << 16);                          \
    float part = h1f * wl;                                                       \
    part += __shfl_xor(part, 16);                                                \
    part += __shfl_xor(part, 32);                                                \
    if (lane < 16) s_pr[(TAU_) & 1][prw + w] = part;                             \
    xcur = xnxt;                                                                 \
    bar_lds();                                                                   \
} while (0)

    // ---- steady loop: tau = 1..511, 2x unrolled with compile-time parity ----
    for (int tau = 1; tau < T_OBS - 1; tau += 2) {
        STEADY(tau,     48, 0);     // tau odd : write par1, read par0
        STEADY(tau + 1,  0, 96);    // tau even: write par0, read par1
    }
    STEADY(T_OBS - 1, 48, 0);       // tau = 511

    // bridge: out(510) from s_pr parity 1 (written at tau=511)
    if (tid < 16) {
        const float* pr = &s_pr[1][tid * PSTR];
        const f32x4 sv = *(const f32x4*)(pr) + *(const f32x4*)(pr + 4)
                       + *(const f32x4*)(pr + 8);
        out[(bb0 + tid) * TT + (T_OBS - 2)] = sv[0] + sv[1] + sv[2] + sv[3] + bl;
    }

    // ---- AR loop: tau = 512..TT; every wave does L1 then (post-bar) L0 ----
    for (int tau = T_OBS; tau <= TT; ++tau) {
        const int wbh = (tau & 1) * 96;           // write parity base (halves)
        const int rbh = 96 - wbh;                 // read parity base (halves)

        const f16x8 B0 = *(const f16x8*)(s_h + nbh + rbh + ko0);
        const f16x8 B1 = *(const f16x8*)(s_h + nbh + rbh + ko1);
        const f16x8 B2 = *(const f16x8*)(s_h + nbh + rbh + ko2);

        // L1 step tau-1
        f32x4 g1a = MF(a1h[0], B0, bv1);
        g1a = MF(a1l[0], B0, g1a);
        g1a = MF(a1h[1], B1, g1a);
        f32x4 g1b = MF(a1l[1], B1, z4);
        g1b = MF(a1h[2], B2, g1b);
        g1b = MF(a1l[2], B2, g1b);
        const f32x4 G1 = g1a + g1b;
        const float h1f = act1(G1, cc1);
        s_h[nbh + wbh + 2 * u + 1] = (_Float16)h1f;
        float part = h1f * wl;
        part += __shfl_xor(part, 16);
        part += __shfl_xor(part, 32);
        if (lane < 16) s_pr[tau & 1][prw + w] = part;

        // L0 step tau MFMA part (input term added after o resolves)
        f32x4 g0a = MF(a0h[0], B0, bv0);
        g0a = MF(a0l[0], B0, g0a);
        g0a = MF(a0h[1], B1, g0a);
        f32x4 g0b = MF(a0l[1], B1, z4);
        g0b = MF(a0h[2], B2, g0b);
        g0b = MF(a0l[2], B2, g0b);
        const f32x4 G0p = g0a + g0b;

        bar_lds();   // mid: s_pr (h1(tau-1) partials) + h1 LDS ready

        // o(tau-1): every wave resolves (needs it for its own L0 tile)
        const float* pr = &s_pr[tau & 1][q * PSTR];
        const f32x4 sv = *(const f32x4*)(pr) + *(const f32x4*)(pr + 4)
                       + *(const f32x4*)(pr + 8);
        const float o = sv[0] + sv[1] + sv[2] + sv[3] + bl;
        if (tid < 16) out[(bb0 + q) * TT + (tau - 1)] = o;
        if (tau < TT) {
            const f32x4 G0 = G0p + wi0v * o;
            const float h0f = act1(G0, cc0);
            s_h[nbh + wbh + 2 * u] = (_Float16)h0f;
        }
        bar_lds();
    }
}

extern "C" void kernel_launch(void* const* d_in, const int* in_sizes, int n_in,
                              void* d_out, int out_size, void* d_ws, size_t ws_size,
                              hipStream_t stream) {
    const float* x    = (const float*)d_in[0];
    const float* Wih0 = (const float*)d_in[1];
    const float* Whh0 = (const float*)d_in[2];
    const float* bih0 = (const float*)d_in[3];
    const float* bhh0 = (const float*)d_in[4];
    const float* Wih1 = (const float*)d_in[5];
    const float* Whh1 = (const float*)d_in[6];
    const float* bih1 = (const float*)d_in[7];
    const float* bhh1 = (const float*)d_in[8];
    const float* Wlin = (const float*)d_in[9];
    const float* blin = (const float*)d_in[10];
    const int*   fut  = (const int*)d_in[11];
    float* out = (float*)d_out;

    const int B    = in_sizes[0] / T_OBS;   // 4096
    const int grid = B / 16;                // 256 blocks -> 1 per CU, 12 waves = 3/SIMD
    lstm2_v12<<<grid, 768, 0, stream>>>(
        x, Wih0, Whh0, bih0, bhh0, Wih1, Whh1, bih1, bhh1, Wlin, blin, fut, out);
}